// Round 17
// baseline (738.778 us; speedup 1.0000x reference)
//
#include <hip/hip_runtime.h>

// ============================================================================
// ROUND 17: r14 operands/swizzle/fragments (proven: 0 conflicts, 1055 TF) with
// the sync schedule collapsed from 8 barriers/K-tile to 2. Per iteration:
//   [24 ds_read + 64 MFMA as ONE schedulable region] ; BAR ;
//   STAGE(t+2 -> cur, 8 loads) ; vmcnt(8) ; BAR
// vmcnt(8) drains exactly tile t+1 (issued one full K-tile earlier -> latency
// already covered); loads never drain to 0 in-loop (T4). r16's 32x32+additive
// swizzle regressed (conflicts 5e7) and is reverted.
// ============================================================================

#define H     4096
#define NROWS 16384
#define NEXP  4
#define NT    64          // K-tiles of 64

typedef __attribute__((ext_vector_type(8))) __bf16 bf16x8;
typedef __attribute__((ext_vector_type(4))) float  f32x4;

#define BAR()    asm volatile("s_barrier" ::: "memory")
#define VMCNT0() asm volatile("s_waitcnt vmcnt(0)" ::: "memory")
#define VMCNT8() asm volatile("s_waitcnt vmcnt(8)" ::: "memory")

__device__ __forceinline__ void gload16(const char* g, char* l) {
    __builtin_amdgcn_global_load_lds(
        (const __attribute__((address_space(1))) void*)g,
        (__attribute__((address_space(3))) void*)l, 16, 0, 0);
}

// ---------------------------------------------------------------------------
// Convert kernels (memory-bound; at HBM roofline, ~121 us total).
// ---------------------------------------------------------------------------
__global__ __launch_bounds__(256) void norm_convert(
    const float* __restrict__ x, const float* __restrict__ nw,
    __bf16* __restrict__ out) {
    const size_t nthread8 = (size_t)NROWS * H / 8;
    for (size_t i = (size_t)blockIdx.x * 256 + threadIdx.x; i < nthread8;
         i += (size_t)gridDim.x * 256) {
        const size_t base = i * 8;
        const int e = (int)(base >> 24);
        const int k = (int)(base & (size_t)(H - 1));
        const float4 v0 = *(const float4*)(x + base);
        const float4 v1 = *(const float4*)(x + base + 4);
        const float4 w0 = *(const float4*)(nw + (size_t)e * H + k);
        const float4 w1 = *(const float4*)(nw + (size_t)e * H + k + 4);
        bf16x8 r;
        r[0] = (__bf16)(v0.x * (w0.x + 1.0f));
        r[1] = (__bf16)(v0.y * (w0.y + 1.0f));
        r[2] = (__bf16)(v0.z * (w0.z + 1.0f));
        r[3] = (__bf16)(v0.w * (w0.w + 1.0f));
        r[4] = (__bf16)(v1.x * (w1.x + 1.0f));
        r[5] = (__bf16)(v1.y * (w1.y + 1.0f));
        r[6] = (__bf16)(v1.z * (w1.z + 1.0f));
        r[7] = (__bf16)(v1.w * (w1.w + 1.0f));
        *(bf16x8*)(out + base) = r;
    }
}

__global__ __launch_bounds__(256) void w_convert(
    const float* __restrict__ wf, __bf16* __restrict__ out) {
    const size_t nthread8 = (size_t)NEXP * H * H / 8;
    for (size_t i = (size_t)blockIdx.x * 256 + threadIdx.x; i < nthread8;
         i += (size_t)gridDim.x * 256) {
        const size_t base = i * 8;
        const float4 v0 = *(const float4*)(wf + base);
        const float4 v1 = *(const float4*)(wf + base + 4);
        bf16x8 r;
        r[0] = (__bf16)v0.x; r[1] = (__bf16)v0.y;
        r[2] = (__bf16)v0.z; r[3] = (__bf16)v0.w;
        r[4] = (__bf16)v1.x; r[5] = (__bf16)v1.y;
        r[6] = (__bf16)v1.z; r[7] = (__bf16)v1.w;
        *(bf16x8*)(out + base) = r;
    }
}

// ---------------------------------------------------------------------------
// 2-barrier/K-tile 256^2 GEMM, 16x16x32 MFMA. 512 threads = 8 waves (2Mx4N),
// per-wave output 128x64 (acc[8][4] of 16x16 fragments).
// ---------------------------------------------------------------------------
__global__ __launch_bounds__(512, 2) void gemm_bf16_2bar(
    const __bf16* __restrict__ A,    // (NROWS, H) bf16
    const __bf16* __restrict__ Wb,   // (NEXP, H, H) bf16
    float* __restrict__ C) {         // (NROWS, H) fp32
    __shared__ __align__(16) char lds[131072];

    const int tid  = threadIdx.x;
    const int lane = tid & 63;
    const int w    = tid >> 6;    // 0..7
    const int wr   = w >> 2;      // 0..1: rows wr*128..+127
    const int wc   = w & 3;       // 0..3: cols wc*64..+63

    // T1: bijective XCD swizzle (1024 blocks, 1024%8==0).
    const int bid = blockIdx.x;
    const int swz = (bid & 7) * 128 + (bid >> 3);
    const int bx  = swz & 15;
    const int by  = swz >> 4;
    const int e   = by >> 4;
    const int row0 = by * 256;
    const int col0 = bx * 256;

    const char* Ab = (const char*)A;
    const char* Bb = (const char*)(Wb + (size_t)e * H * H);

    // Staging (r14 exact): thread stages row srow (+128 for 2nd gload), 16B
    // at inverse-swizzled source slot; LDS dest linear (tid*16).
    const int    srow  = tid >> 2;
    const int    sslot = (((tid & 3) ^ ((tid >> 3) & 3)) << 4);
    const size_t a_g0  = ((size_t)(row0 + srow) * H) * 2 + sslot;
    const size_t a_g1  = a_g0 + (size_t)128 * H * 2;
    const size_t b_g0  = ((size_t)(col0 + srow) * H) * 2 + sslot;
    const size_t b_g1  = b_g0 + (size_t)128 * H * 2;
    const int    lds_t = tid * 16;

    // Read constants (r14 exact): phys slot = slog ^ ((l15>>1)&3).
    const int l15   = lane & 15;
    const int slog  = lane >> 4;
    const int pslot = ((slog ^ ((l15 >> 1) & 3)) << 4);

    f32x4 acc[8][4] = {};

#define STAGE(base, koff, g0, g1, ldst)                       \
    do {                                                      \
        gload16(base + g0 + (koff), (ldst) + lds_t);          \
        gload16(base + g1 + (koff), (ldst) + 8192 + lds_t);   \
    } while (0)
#define LDF(dst, gran, rowe) \
    dst = *(const bf16x8*)((gran) + (rowe) * 64 + pslot)

    // ---- prologue: stage tile0 (8 loads) + tile1 (8 loads); vmcnt(8)
    //      drains exactly tile0; tile1 stays in flight. ----
    {
        char* A0 = lds;            char* B0 = lds + 32768;
        char* A1 = lds + 65536;    char* B1 = lds + 98304;
        STAGE(Ab, 0,   a_g0, a_g1, A0);
        STAGE(Ab, 64,  a_g0, a_g1, A0 + 16384);
        STAGE(Bb, 0,   b_g0, b_g1, B0);
        STAGE(Bb, 64,  b_g0, b_g1, B0 + 16384);
        STAGE(Ab, 128, a_g0, a_g1, A1);
        STAGE(Ab, 192, a_g0, a_g1, A1 + 16384);
        STAGE(Bb, 128, b_g0, b_g1, B1);
        STAGE(Bb, 192, b_g0, b_g1, B1 + 16384);
        VMCNT8();
        BAR();
    }

    for (int t = 0; t < NT; ++t) {
        char* curA = lds + (t & 1) * 65536;
        char* curB = curA + 32768;

        // ---- one schedulable region: 24 ds_read + 64 MFMA ----
        #pragma unroll
        for (int kh = 0; kh < 2; ++kh) {
            const char* gA = curA + kh * 16384;
            const char* gB = curB + kh * 16384;
            bf16x8 a[8], b[4];
            #pragma unroll
            for (int n = 0; n < 4; ++n) LDF(b[n], gB, wc * 64 + n * 16 + l15);
            #pragma unroll
            for (int m = 0; m < 8; ++m) LDF(a[m], gA, wr * 128 + m * 16 + l15);
            __builtin_amdgcn_s_setprio(1);
            #pragma unroll
            for (int m = 0; m < 8; ++m)
                #pragma unroll
                for (int n = 0; n < 4; ++n)
                    acc[m][n] = __builtin_amdgcn_mfma_f32_16x16x32_bf16(
                        a[m], b[n], acc[m][n], 0, 0, 0);
            __builtin_amdgcn_s_setprio(0);
        }

        BAR();   // all waves done reading cur (reads consumed by MFMAs above)

        if (t + 2 < NT) {
            // stage tile t+2 into cur (just freed); 8 loads -> 16 outstanding
            const size_t kn = (size_t)(t + 2) * 128;
            STAGE(Ab, kn,      a_g0, a_g1, curA);
            STAGE(Ab, kn + 64, a_g0, a_g1, curA + 16384);
            STAGE(Bb, kn,      b_g0, b_g1, curB);
            STAGE(Bb, kn + 64, b_g0, b_g1, curB + 16384);
            VMCNT8();   // drains exactly tile t+1 (issued one K-tile ago)
        } else if (t + 1 < NT) {
            VMCNT0();   // edge: drain the final prefetched tile
        }
        BAR();   // tile t+1 visible to all waves
    }

    // Epilogue: C/D layout col = lane&15, row = (lane>>4)*4 + j  [m89].
    const int fq = slog * 4;
    #pragma unroll
    for (int m8 = 0; m8 < 8; ++m8) {
        #pragma unroll
        for (int n = 0; n < 4; ++n) {
            #pragma unroll
            for (int j = 0; j < 4; ++j) {
                const int gr = row0 + wr * 128 + m8 * 16 + fq + j;
                const int gc = col0 + wc * 64 + n * 16 + l15;
                C[(size_t)gr * H + gc] = acc[m8][n][j];
            }
        }
    }
#undef STAGE
#undef LDF
}

// ---------------------------------------------------------------------------
// FALLBACK (ws too small): round-12 fused kernel (verified passing, 430 TF).
// ---------------------------------------------------------------------------
#define BM 128
#define BN 128
#define BK 64
__global__ __launch_bounds__(256, 2) void fused_norm_gemm_f32w(
    const float* __restrict__ X, const float* __restrict__ NW,
    const float* __restrict__ Wf, float* __restrict__ C) {
    __shared__ __align__(16) __bf16 As[BM * BK];
    __shared__ __align__(16) __bf16 Bs[BN * BK];
    const int tid = threadIdx.x, lane = tid & 63, w = tid >> 6;
    const int wr = w >> 1, wc = w & 1;
    const int row0 = blockIdx.y * BM, col0 = blockIdx.x * BN;
    f32x4 acc[4][4] = {};
    const int a_kc = (tid & 7) * 8, a_r0 = tid >> 3;
    char* AsB = (char*)As; char* BsB = (char*)Bs;
    for (int kt = 0; kt < H; kt += BK) {
        __syncthreads();
        float4 xv[4][2], bv[4][2];
        #pragma unroll
        for (int it = 0; it < 4; ++it) {
            const float* xp = X + (size_t)(row0 + it * 32 + a_r0) * H + kt + a_kc;
            xv[it][0] = *(const float4*)xp; xv[it][1] = *(const float4*)(xp + 4);
        }
        #pragma unroll
        for (int it = 0; it < 4; ++it) {
            const float* bp = Wf + (size_t)(col0 + it * 32 + a_r0) * H + kt + a_kc;
            bv[it][0] = *(const float4*)bp; bv[it][1] = *(const float4*)(bp + 4);
        }
        float4 w0 = *(const float4*)(NW + kt + a_kc);
        float4 w1 = *(const float4*)(NW + kt + a_kc + 4);
        w0.x += 1.0f; w0.y += 1.0f; w0.z += 1.0f; w0.w += 1.0f;
        w1.x += 1.0f; w1.y += 1.0f; w1.z += 1.0f; w1.w += 1.0f;
        #pragma unroll
        for (int it = 0; it < 4; ++it) {
            bf16x8 r;
            r[0] = (__bf16)(xv[it][0].x * w0.x); r[1] = (__bf16)(xv[it][0].y * w0.y);
            r[2] = (__bf16)(xv[it][0].z * w0.z); r[3] = (__bf16)(xv[it][0].w * w0.w);
            r[4] = (__bf16)(xv[it][1].x * w1.x); r[5] = (__bf16)(xv[it][1].y * w1.y);
            r[6] = (__bf16)(xv[it][1].z * w1.z); r[7] = (__bf16)(xv[it][1].w * w1.w);
            *(bf16x8*)(AsB + (it * 32 + a_r0) * 128 + a_kc * 2) = r;
        }
        #pragma unroll
        for (int it = 0; it < 4; ++it) {
            bf16x8 r;
            r[0] = (__bf16)bv[it][0].x; r[1] = (__bf16)bv[it][0].y;
            r[2] = (__bf16)bv[it][0].z; r[3] = (__bf16)bv[it][0].w;
            r[4] = (__bf16)bv[it][1].x; r[5] = (__bf16)bv[it][1].y;
            r[6] = (__bf16)bv[it][1].z; r[7] = (__bf16)bv[it][1].w;
            *(bf16x8*)(BsB + (it * 32 + a_r0) * 128 + a_kc * 2) = r;
        }
        __syncthreads();
        #pragma unroll
        for (int kh = 0; kh < 2; ++kh) {
            const int kb = kh * 4 + (lane >> 4);
            bf16x8 af[4], bfr[4];
            #pragma unroll
            for (int m = 0; m < 4; ++m) {
                const int r = wr * 64 + m * 16 + (lane & 15);
                af[m] = *(const bf16x8*)(AsB + r * 128 + kb * 16);
            }
            #pragma unroll
            for (int n = 0; n < 4; ++n) {
                const int r = wc * 64 + n * 16 + (lane & 15);
                bfr[n] = *(const bf16x8*)(BsB + r * 128 + kb * 16);
            }
            #pragma unroll
            for (int m = 0; m < 4; ++m)
                #pragma unroll
                for (int n = 0; n < 4; ++n)
                    acc[m][n] = __builtin_amdgcn_mfma_f32_16x16x32_bf16(
                        af[m], bfr[n], acc[m][n], 0, 0, 0);
        }
    }
    const int fr = lane & 15, fq = (lane >> 4) * 4;
    #pragma unroll
    for (int m = 0; m < 4; ++m)
        #pragma unroll
        for (int n = 0; n < 4; ++n)
            #pragma unroll
            for (int j = 0; j < 4; ++j) {
                const int gr = row0 + wr * 64 + m * 16 + fq + j;
                const int gc = col0 + wc * 64 + n * 16 + fr;
                C[(size_t)gr * H + gc] = acc[m][n][j];
            }
}

// ---------------------------------------------------------------------------
// Host. d_in[2] is FP32 (npz upcast). ws: [0,134MB)=normed-x bf16,
// [134MB,268MB)=W bf16. Fallback if ws too small.
// ---------------------------------------------------------------------------
extern "C" void kernel_launch(void* const* d_in, const int* in_sizes, int n_in,
                              void* d_out, int out_size, void* d_ws, size_t ws_size,
                              hipStream_t stream) {
    (void)in_sizes; (void)n_in; (void)out_size;
    const float* x  = (const float*)d_in[0];
    const float* nw = (const float*)d_in[1];
    const float* wf = (const float*)d_in[2];
    float* out = (float*)d_out;

    const size_t xe_bytes = (size_t)NROWS * H * 2;
    const size_t we_bytes = (size_t)NEXP * H * H * 2;

    if (ws_size >= xe_bytes + we_bytes) {
        __bf16* ws_x = (__bf16*)d_ws;
        __bf16* ws_w = (__bf16*)((char*)d_ws + xe_bytes);
        norm_convert<<<2048, 256, 0, stream>>>(x, nw, ws_x);
        w_convert<<<2048, 256, 0, stream>>>(wf, ws_w);
        gemm_bf16_2bar<<<1024, 512, 0, stream>>>(ws_x, ws_w, out);
    } else {
        dim3 grid(H / BN, 4096 / BM);
        for (int i = 0; i < NEXP; ++i) {
            fused_norm_gemm_f32w<<<grid, 256, 0, stream>>>(
                x + (size_t)i * 4096 * H, nw + (size_t)i * H,
                wf + (size_t)i * H * H, out + (size_t)i * 4096 * H);
        }
    }
}

// Round 18
// 637.807 us; speedup vs baseline: 1.1583x; 1.1583x over previous
//
#include <hip/hip_runtime.h>

// ============================================================================
// ROUND 18: r14 EXACT schedule (best measured: 521 us GEMM / 1055 TF /
// MfmaUtil 47.7 / 0 conflicts) with ONE intra-phase reorder: ds_reads issued
// BEFORE the stage gloads (m201's documented order). r15/r16/r17 alternatives
// all regressed and are reverted.
// Pipeline: norm_convert + w_convert (HBM-roofline, 121 us) -> 8-phase 256^2
// GEMM, 16x16x32 MFMA, XOR swizzle, vmcnt(4)@P2/P4.
// ============================================================================

#define H     4096
#define NROWS 16384
#define NEXP  4
#define NT    64          // K-tiles of 64

typedef __attribute__((ext_vector_type(8))) __bf16 bf16x8;
typedef __attribute__((ext_vector_type(4))) float  f32x4;

#define BAR()    asm volatile("s_barrier" ::: "memory")
#define VMCNT0() asm volatile("s_waitcnt vmcnt(0)" ::: "memory")
#define VMCNT4() asm volatile("s_waitcnt vmcnt(4)" ::: "memory")

__device__ __forceinline__ void gload16(const char* g, char* l) {
    __builtin_amdgcn_global_load_lds(
        (const __attribute__((address_space(1))) void*)g,
        (__attribute__((address_space(3))) void*)l, 16, 0, 0);
}

// ---------------------------------------------------------------------------
// Convert kernels (memory-bound; at HBM roofline, ~121 us total).
// ---------------------------------------------------------------------------
__global__ __launch_bounds__(256) void norm_convert(
    const float* __restrict__ x, const float* __restrict__ nw,
    __bf16* __restrict__ out) {
    const size_t nthread8 = (size_t)NROWS * H / 8;
    for (size_t i = (size_t)blockIdx.x * 256 + threadIdx.x; i < nthread8;
         i += (size_t)gridDim.x * 256) {
        const size_t base = i * 8;
        const int e = (int)(base >> 24);
        const int k = (int)(base & (size_t)(H - 1));
        const float4 v0 = *(const float4*)(x + base);
        const float4 v1 = *(const float4*)(x + base + 4);
        const float4 w0 = *(const float4*)(nw + (size_t)e * H + k);
        const float4 w1 = *(const float4*)(nw + (size_t)e * H + k + 4);
        bf16x8 r;
        r[0] = (__bf16)(v0.x * (w0.x + 1.0f));
        r[1] = (__bf16)(v0.y * (w0.y + 1.0f));
        r[2] = (__bf16)(v0.z * (w0.z + 1.0f));
        r[3] = (__bf16)(v0.w * (w0.w + 1.0f));
        r[4] = (__bf16)(v1.x * (w1.x + 1.0f));
        r[5] = (__bf16)(v1.y * (w1.y + 1.0f));
        r[6] = (__bf16)(v1.z * (w1.z + 1.0f));
        r[7] = (__bf16)(v1.w * (w1.w + 1.0f));
        *(bf16x8*)(out + base) = r;
    }
}

__global__ __launch_bounds__(256) void w_convert(
    const float* __restrict__ wf, __bf16* __restrict__ out) {
    const size_t nthread8 = (size_t)NEXP * H * H / 8;
    for (size_t i = (size_t)blockIdx.x * 256 + threadIdx.x; i < nthread8;
         i += (size_t)gridDim.x * 256) {
        const size_t base = i * 8;
        const float4 v0 = *(const float4*)(wf + base);
        const float4 v1 = *(const float4*)(wf + base + 4);
        bf16x8 r;
        r[0] = (__bf16)v0.x; r[1] = (__bf16)v0.y;
        r[2] = (__bf16)v0.z; r[3] = (__bf16)v0.w;
        r[4] = (__bf16)v1.x; r[5] = (__bf16)v1.y;
        r[6] = (__bf16)v1.z; r[7] = (__bf16)v1.w;
        *(bf16x8*)(out + base) = r;
    }
}

// ---------------------------------------------------------------------------
// 8-phase 256^2 GEMM. 512 threads = 8 waves (2 row-halves x 4 col-quarters).
// ---------------------------------------------------------------------------
__global__ __launch_bounds__(512, 2) void gemm_bf16_8ph(
    const __bf16* __restrict__ A,    // (NROWS, H) bf16
    const __bf16* __restrict__ Wb,   // (NEXP, H, H) bf16
    float* __restrict__ C) {         // (NROWS, H) fp32
    __shared__ __align__(16) char lds[131072];

    const int tid  = threadIdx.x;
    const int lane = tid & 63;
    const int w    = tid >> 6;    // 0..7
    const int wr   = w >> 2;      // 0..1: rows wr*128..+127
    const int wc   = w & 3;       // 0..3: cols wc*64..+63

    // T1: bijective XCD swizzle (1024 blocks, 1024%8==0).
    const int bid = blockIdx.x;
    const int swz = (bid & 7) * 128 + (bid >> 3);
    const int bx  = swz & 15;
    const int by  = swz >> 4;
    const int e   = by >> 4;
    const int row0 = by * 256;
    const int col0 = bx * 256;

    const char* Ab = (const char*)A;
    const char* Bb = (const char*)(Wb + (size_t)e * H * H);

    const int    srow  = tid >> 2;
    const int    sslot = (((tid & 3) ^ ((tid >> 3) & 3)) << 4);
    const size_t a_g0  = ((size_t)(row0 + srow) * H) * 2 + sslot;
    const size_t a_g1  = a_g0 + (size_t)128 * H * 2;
    const size_t b_g0  = ((size_t)(col0 + srow) * H) * 2 + sslot;
    const size_t b_g1  = b_g0 + (size_t)128 * H * 2;
    const int    lds_t = tid * 16;

    const int l15   = lane & 15;
    const int slog  = lane >> 4;
    const int pslot = ((slog ^ ((l15 >> 1) & 3)) << 4);

    f32x4 acc[8][4] = {};

#define STAGE(base, koff, g0, g1, ldst)                       \
    do {                                                      \
        gload16(base + g0 + (koff), (ldst) + lds_t);          \
        gload16(base + g1 + (koff), (ldst) + 8192 + lds_t);   \
    } while (0)
#define LDF(dst, gran, rowe) \
    dst = *(const bf16x8*)((gran) + (rowe) * 64 + pslot)

    // ---- prologue: stage all 4 granules of tile 0, drain, barrier ----
    {
        char* A0 = lds;
        char* B0 = lds + 32768;
        STAGE(Ab, 0,  a_g0, a_g1, A0);
        STAGE(Bb, 0,  b_g0, b_g1, B0);
        STAGE(Ab, 64, a_g0, a_g1, A0 + 16384);
        STAGE(Bb, 64, b_g0, b_g1, B0 + 16384);
        VMCNT0();
        BAR();
    }

    for (int t = 0; t < NT; ++t) {
        char* curA = lds + (t & 1) * 65536;
        char* curB = curA + 32768;
        char* nxtA = lds + ((t & 1) ^ 1) * 65536;
        char* nxtB = nxtA + 32768;
        const size_t kn0 = (size_t)(t + 1) * 128;
        const size_t kn1 = kn0 + 64;
        const bool   st  = (t + 1 < NT);

        bf16x8 a[4], b0[4], b1[4];

        // ---- P1: read B-kh0, A-kh0 rows 0-63 | stage A-kh0(t+1) | MFMA ----
        #pragma unroll
        for (int n = 0; n < 4; ++n) LDF(b0[n], curB, wc * 64 + n * 16 + l15);
        #pragma unroll
        for (int m = 0; m < 4; ++m) LDF(a[m], curA, wr * 128 + m * 16 + l15);
        if (st) STAGE(Ab, kn0, a_g0, a_g1, nxtA);
        BAR();
        __builtin_amdgcn_s_setprio(1);
        #pragma unroll
        for (int m = 0; m < 4; ++m)
            #pragma unroll
            for (int n = 0; n < 4; ++n)
                acc[m][n] = __builtin_amdgcn_mfma_f32_16x16x32_bf16(
                    a[m], b0[n], acc[m][n], 0, 0, 0);
        __builtin_amdgcn_s_setprio(0);
        BAR();

        // ---- P2: read A-kh0 rows 64-127 | stage B-kh0(t+1) | MFMA | vm ----
        #pragma unroll
        for (int m = 0; m < 4; ++m) LDF(a[m], curA, wr * 128 + 64 + m * 16 + l15);
        if (st) STAGE(Bb, kn0, b_g0, b_g1, nxtB);
        BAR();
        __builtin_amdgcn_s_setprio(1);
        #pragma unroll
        for (int m = 0; m < 4; ++m)
            #pragma unroll
            for (int n = 0; n < 4; ++n)
                acc[4 + m][n] = __builtin_amdgcn_mfma_f32_16x16x32_bf16(
                    a[m], b0[n], acc[4 + m][n], 0, 0, 0);
        __builtin_amdgcn_s_setprio(0);
        if (st) VMCNT4(); else VMCNT0();   // A-kh1(t), B-kh1(t) resident
        BAR();

        // ---- P3: read B-kh1, A-kh1 rows 0-63 | stage A-kh1(t+1) | MFMA ----
        #pragma unroll
        for (int n = 0; n < 4; ++n) LDF(b1[n], curB + 16384, wc * 64 + n * 16 + l15);
        #pragma unroll
        for (int m = 0; m < 4; ++m) LDF(a[m], curA + 16384, wr * 128 + m * 16 + l15);
        if (st) STAGE(Ab, kn1, a_g0, a_g1, nxtA + 16384);
        BAR();
        __builtin_amdgcn_s_setprio(1);
        #pragma unroll
        for (int m = 0; m < 4; ++m)
            #pragma unroll
            for (int n = 0; n < 4; ++n)
                acc[m][n] = __builtin_amdgcn_mfma_f32_16x16x32_bf16(
                    a[m], b1[n], acc[m][n], 0, 0, 0);
        __builtin_amdgcn_s_setprio(0);
        BAR();

        // ---- P4: read A-kh1 rows 64-127 | stage B-kh1(t+1) | MFMA | vm ----
        #pragma unroll
        for (int m = 0; m < 4; ++m) LDF(a[m], curA + 16384, wr * 128 + 64 + m * 16 + l15);
        if (st) STAGE(Bb, kn1, b_g0, b_g1, nxtB + 16384);
        BAR();
        __builtin_amdgcn_s_setprio(1);
        #pragma unroll
        for (int m = 0; m < 4; ++m)
            #pragma unroll
            for (int n = 0; n < 4; ++n)
                acc[4 + m][n] = __builtin_amdgcn_mfma_f32_16x16x32_bf16(
                    a[m], b1[n], acc[4 + m][n], 0, 0, 0);
        __builtin_amdgcn_s_setprio(0);
        if (st) VMCNT4();                  // A-kh0(t+1), B-kh0(t+1) resident
        BAR();
    }

    // Epilogue: C/D layout col = lane&15, row = (lane>>4)*4 + j  [m89].
    const int fq = slog * 4;
    #pragma unroll
    for (int m8 = 0; m8 < 8; ++m8) {
        #pragma unroll
        for (int n = 0; n < 4; ++n) {
            #pragma unroll
            for (int j = 0; j < 4; ++j) {
                const int gr = row0 + wr * 128 + m8 * 16 + fq + j;
                const int gc = col0 + wc * 64 + n * 16 + l15;
                C[(size_t)gr * H + gc] = acc[m8][n][j];
            }
        }
    }
#undef STAGE
#undef LDF
}

// ---------------------------------------------------------------------------
// FALLBACK (ws too small): round-12 fused kernel (verified passing, 430 TF).
// ---------------------------------------------------------------------------
#define BM 128
#define BN 128
#define BK 64
__global__ __launch_bounds__(256, 2) void fused_norm_gemm_f32w(
    const float* __restrict__ X, const float* __restrict__ NW,
    const float* __restrict__ Wf, float* __restrict__ C) {
    __shared__ __align__(16) __bf16 As[BM * BK];
    __shared__ __align__(16) __bf16 Bs[BN * BK];
    const int tid = threadIdx.x, lane = tid & 63, w = tid >> 6;
    const int wr = w >> 1, wc = w & 1;
    const int row0 = blockIdx.y * BM, col0 = blockIdx.x * BN;
    f32x4 acc[4][4] = {};
    const int a_kc = (tid & 7) * 8, a_r0 = tid >> 3;
    char* AsB = (char*)As; char* BsB = (char*)Bs;
    for (int kt = 0; kt < H; kt += BK) {
        __syncthreads();
        float4 xv[4][2], bv[4][2];
        #pragma unroll
        for (int it = 0; it < 4; ++it) {
            const float* xp = X + (size_t)(row0 + it * 32 + a_r0) * H + kt + a_kc;
            xv[it][0] = *(const float4*)xp; xv[it][1] = *(const float4*)(xp + 4);
        }
        #pragma unroll
        for (int it = 0; it < 4; ++it) {
            const float* bp = Wf + (size_t)(col0 + it * 32 + a_r0) * H + kt + a_kc;
            bv[it][0] = *(const float4*)bp; bv[it][1] = *(const float4*)(bp + 4);
        }
        float4 w0 = *(const float4*)(NW + kt + a_kc);
        float4 w1 = *(const float4*)(NW + kt + a_kc + 4);
        w0.x += 1.0f; w0.y += 1.0f; w0.z += 1.0f; w0.w += 1.0f;
        w1.x += 1.0f; w1.y += 1.0f; w1.z += 1.0f; w1.w += 1.0f;
        #pragma unroll
        for (int it = 0; it < 4; ++it) {
            bf16x8 r;
            r[0] = (__bf16)(xv[it][0].x * w0.x); r[1] = (__bf16)(xv[it][0].y * w0.y);
            r[2] = (__bf16)(xv[it][0].z * w0.z); r[3] = (__bf16)(xv[it][0].w * w0.w);
            r[4] = (__bf16)(xv[it][1].x * w1.x); r[5] = (__bf16)(xv[it][1].y * w1.y);
            r[6] = (__bf16)(xv[it][1].z * w1.z); r[7] = (__bf16)(xv[it][1].w * w1.w);
            *(bf16x8*)(AsB + (it * 32 + a_r0) * 128 + a_kc * 2) = r;
        }
        #pragma unroll
        for (int it = 0; it < 4; ++it) {
            bf16x8 r;
            r[0] = (__bf16)bv[it][0].x; r[1] = (__bf16)bv[it][0].y;
            r[2] = (__bf16)bv[it][0].z; r[3] = (__bf16)bv[it][0].w;
            r[4] = (__bf16)bv[it][1].x; r[5] = (__bf16)bv[it][1].y;
            r[6] = (__bf16)bv[it][1].z; r[7] = (__bf16)bv[it][1].w;
            *(bf16x8*)(BsB + (it * 32 + a_r0) * 128 + a_kc * 2) = r;
        }
        __syncthreads();
        #pragma unroll
        for (int kh = 0; kh < 2; ++kh) {
            const int kb = kh * 4 + (lane >> 4);
            bf16x8 af[4], bfr[4];
            #pragma unroll
            for (int m = 0; m < 4; ++m) {
                const int r = wr * 64 + m * 16 + (lane & 15);
                af[m] = *(const bf16x8*)(AsB + r * 128 + kb * 16);
            }
            #pragma unroll
            for (int n = 0; n < 4; ++n) {
                const int r = wc * 64 + n * 16 + (lane & 15);
                bfr[n] = *(const bf16x8*)(BsB + r * 128 + kb * 16);
            }
            #pragma unroll
            for (int m = 0; m < 4; ++m)
                #pragma unroll
                for (int n = 0; n < 4; ++n)
                    acc[m][n] = __builtin_amdgcn_mfma_f32_16x16x32_bf16(
                        af[m], bfr[n], acc[m][n], 0, 0, 0);
        }
    }
    const int fr = lane & 15, fq = (lane >> 4) * 4;
    #pragma unroll
    for (int m = 0; m < 4; ++m)
        #pragma unroll
        for (int n = 0; n < 4; ++n)
            #pragma unroll
            for (int j = 0; j < 4; ++j) {
                const int gr = row0 + wr * 64 + m * 16 + fq + j;
                const int gc = col0 + wc * 64 + n * 16 + fr;
                C[(size_t)gr * H + gc] = acc[m][n][j];
            }
}

// ---------------------------------------------------------------------------
// Host. d_in[2] is FP32 (npz upcast). ws: [0,134MB)=normed-x bf16,
// [134MB,268MB)=W bf16. Fallback if ws too small.
// ---------------------------------------------------------------------------
extern "C" void kernel_launch(void* const* d_in, const int* in_sizes, int n_in,
                              void* d_out, int out_size, void* d_ws, size_t ws_size,
                              hipStream_t stream) {
    (void)in_sizes; (void)n_in; (void)out_size;
    const float* x  = (const float*)d_in[0];
    const float* nw = (const float*)d_in[1];
    const float* wf = (const float*)d_in[2];
    float* out = (float*)d_out;

    const size_t xe_bytes = (size_t)NROWS * H * 2;
    const size_t we_bytes = (size_t)NEXP * H * H * 2;

    if (ws_size >= xe_bytes + we_bytes) {
        __bf16* ws_x = (__bf16*)d_ws;
        __bf16* ws_w = (__bf16*)((char*)d_ws + xe_bytes);
        norm_convert<<<2048, 256, 0, stream>>>(x, nw, ws_x);
        w_convert<<<2048, 256, 0, stream>>>(wf, ws_w);
        gemm_bf16_8ph<<<1024, 512, 0, stream>>>(ws_x, ws_w, out);
    } else {
        dim3 grid(H / BN, 4096 / BM);
        for (int i = 0; i < NEXP; ++i) {
            fused_norm_gemm_f32w<<<grid, 256, 0, stream>>>(
                x + (size_t)i * 4096 * H, nw + (size_t)i * H,
                wf + (size_t)i * H * H, out + (size_t)i * 4096 * H);
        }
    }
}